// Round 1
// baseline (613.549 us; speedup 1.0000x reference)
//
#include <hip/hip_runtime.h>

// Problem dims (fixed)
#define NB 16
#define CD 128
#define HD 64
#define WD 64
#define SD 4096   // H*W
#define K7 896    // 7*C

// GEMM tiling: 64x64 tile, BK=16, 256 threads, 4x4 accum per thread
#define BM 64
#define BN 64
#define BK 16
#define LDP (BM + 4)   // pad so [k][m*4] float4 reads stay 16B aligned (68*4=272=17*16)

// ---------------------------------------------------------------------------
// Kernel 1: T8[n, c1, k'] = (1/64) * sum_s x[n,c1,s] * T3[n,k',s]
//   T3[n,k'=(c2*7+kk),s=(i,j)] = p3[k'] * p2[c2*64+j] * x[n,c2,i+2kk-6,j] (0 OOB rows)
// GEMM per n: (128 x 896), K = 4096. Both operands row-major along K.
// ---------------------------------------------------------------------------
__global__ __launch_bounds__(256)
void t8_kernel(const float* __restrict__ x, const float* __restrict__ p2,
               const float* __restrict__ p3, float* __restrict__ t8) {
  __shared__ float As[BK][LDP];
  __shared__ float Bs[BK][LDP];
  const int n  = blockIdx.z;
  const int m0 = blockIdx.y * BM;   // c1 base
  const int n0 = blockIdx.x * BN;   // k' base
  const int t  = threadIdx.x;
  const int tm = t >> 4, tn = t & 15;
  const int lm = t >> 2;            // 0..63 staging row
  const int lk = (t & 3) << 2;      // 0,4,8,12 staging k

  const float* xn = x + (size_t)n * CD * SD;

  // per-thread constants for on-the-fly T3 row (k' = n0 + lm)
  const int   kp   = n0 + lm;
  const int   c2   = kp / 7;
  const int   kk   = kp - c2 * 7;
  const float p3v  = p3[kp];
  const int   drow = 2 * kk - 6;
  const float* xplane = xn + (size_t)c2 * SD;
  const float* p2c    = p2 + c2 * WD;

  float acc[4][4] = {};
  for (int s0 = 0; s0 < SD; s0 += BK) {   // BK=16 chunk always within one image row
    { // stage A (x row m0+lm), transposed into LDS
      const float4 av = *(const float4*)(xn + (size_t)(m0 + lm) * SD + (s0 + lk));
      As[lk + 0][lm] = av.x; As[lk + 1][lm] = av.y;
      As[lk + 2][lm] = av.z; As[lk + 3][lm] = av.w;
    }
    { // stage B = T3 row kp, generated on the fly
      const int i  = s0 >> 6;
      const int j  = (s0 & 63) + lk;
      const int ip = i + drow;
      float4 bv = make_float4(0.f, 0.f, 0.f, 0.f);
      if ((unsigned)ip < (unsigned)HD)
        bv = *(const float4*)(xplane + ip * WD + j);
      Bs[lk + 0][lm] = bv.x * p3v * p2c[j + 0];
      Bs[lk + 1][lm] = bv.y * p3v * p2c[j + 1];
      Bs[lk + 2][lm] = bv.z * p3v * p2c[j + 2];
      Bs[lk + 3][lm] = bv.w * p3v * p2c[j + 3];
    }
    __syncthreads();
#pragma unroll
    for (int k = 0; k < BK; ++k) {
      const float4 a4 = *(const float4*)&As[k][tm << 2];
      const float4 b4 = *(const float4*)&Bs[k][tn << 2];
      const float ar[4] = {a4.x, a4.y, a4.z, a4.w};
      const float br[4] = {b4.x, b4.y, b4.z, b4.w};
#pragma unroll
      for (int r = 0; r < 4; ++r)
#pragma unroll
        for (int c = 0; c < 4; ++c)
          acc[r][c] = fmaf(ar[r], br[c], acc[r][c]);
    }
    __syncthreads();
  }
  float* orow = t8 + ((size_t)n * CD + (m0 + (tm << 2))) * K7 + n0 + (tn << 2);
#pragma unroll
  for (int r = 0; r < 4; ++r) {
    const float4 v = make_float4(acc[r][0] * (1.f / 64.f), acc[r][1] * (1.f / 64.f),
                                 acc[r][2] * (1.f / 64.f), acc[r][3] * (1.f / 64.f));
    *(float4*)(orow + (size_t)r * K7) = v;
  }
}

// ---------------------------------------------------------------------------
// Kernel 2: M = T8 (2048 x 896) * W7 (896 x 896) * (1/sqrt(896))
//   W7 viewed as (k', c2*7+q) row-major = native layout of w7 (C*7, C, 1, 7).
// ---------------------------------------------------------------------------
__global__ __launch_bounds__(256)
void m_kernel(const float* __restrict__ t8, const float* __restrict__ w7,
              float* __restrict__ mm) {
  __shared__ float As[BK][LDP];
  __shared__ float Bs[BK][LDP];
  const int m0 = blockIdx.y * BM;   // row base in 2048 (= n*128 + c)
  const int n0 = blockIdx.x * BN;   // col base in 896
  const int t  = threadIdx.x;
  const int tm = t >> 4, tn = t & 15;
  const int lm  = t >> 2;
  const int lk  = (t & 3) << 2;
  const int lkb = t >> 4;           // 0..15 B staging row (k)
  const int lnb = (t & 15) << 2;    // B staging col

  float acc[4][4] = {};
  for (int k0 = 0; k0 < K7; k0 += BK) {
    {
      const float4 av = *(const float4*)(t8 + (size_t)(m0 + lm) * K7 + (k0 + lk));
      As[lk + 0][lm] = av.x; As[lk + 1][lm] = av.y;
      As[lk + 2][lm] = av.z; As[lk + 3][lm] = av.w;
    }
    {
      const float4 bv = *(const float4*)(w7 + (size_t)(k0 + lkb) * K7 + (n0 + lnb));
      *(float4*)&Bs[lkb][lnb] = bv;
    }
    __syncthreads();
#pragma unroll
    for (int k = 0; k < BK; ++k) {
      const float4 a4 = *(const float4*)&As[k][tm << 2];
      const float4 b4 = *(const float4*)&Bs[k][tn << 2];
      const float ar[4] = {a4.x, a4.y, a4.z, a4.w};
      const float br[4] = {b4.x, b4.y, b4.z, b4.w};
#pragma unroll
      for (int r = 0; r < 4; ++r)
#pragma unroll
        for (int c = 0; c < 4; ++c)
          acc[r][c] = fmaf(ar[r], br[c], acc[r][c]);
    }
    __syncthreads();
  }
  const float sc = 0.033407655f;   // 1/sqrt(896)
  float* orow = mm + (size_t)(m0 + (tm << 2)) * K7 + n0 + (tn << 2);
#pragma unroll
  for (int r = 0; r < 4; ++r) {
    const float4 v = make_float4(acc[r][0] * sc, acc[r][1] * sc,
                                 acc[r][2] * sc, acc[r][3] * sc);
    *(float4*)(orow + (size_t)r * K7) = v;
  }
}

// ---------------------------------------------------------------------------
// Kernel 3: out[n,c,s=(i,j)] = sum_{k2=(c2*7+q)} M[n,c,k2]*x[n,c2,i,j+q-3] - t6[n,c,i,j]
//   t6[n,c,i,j] = sum_r w6[c*3+r] * p4[c,i',jm]*x[n,c,i',jm], i'=i+3r-3, jm=(j-1)&63
// GEMM per n: (128 x 4096), K = 896. N-tile of 64 = exactly one image row i.
// ---------------------------------------------------------------------------
__global__ __launch_bounds__(256)
void out_kernel(const float* __restrict__ x, const float* __restrict__ mm,
                const float* __restrict__ p4, const float* __restrict__ w6,
                float* __restrict__ outp) {
  __shared__ float As[BK][LDP];
  __shared__ float Bs[BK][LDP];
  const int n  = blockIdx.z;
  const int m0 = blockIdx.y * BM;   // c base
  const int s0 = blockIdx.x * BN;   // s base (one full row)
  const int i  = s0 >> 6;
  const int t  = threadIdx.x;
  const int tm = t >> 4, tn = t & 15;
  const int lm  = t >> 2;
  const int lk  = (t & 3) << 2;
  const int lkb = t >> 4;
  const int lnb = (t & 15) << 2;

  const float* xn = x  + (size_t)n * CD * SD;
  const float* Mn = mm + (size_t)n * CD * K7;

  float acc[4][4] = {};
  for (int k0 = 0; k0 < K7; k0 += BK) {
    {
      const float4 av = *(const float4*)(Mn + (size_t)(m0 + lm) * K7 + (k0 + lk));
      As[lk + 0][lm] = av.x; As[lk + 1][lm] = av.y;
      As[lk + 2][lm] = av.z; As[lk + 3][lm] = av.w;
    }
    { // B = x row i of channel c2, shifted by q-3, zero at edges
      const int k2 = k0 + lkb;
      const int c2 = k2 / 7;
      const int q  = k2 - c2 * 7;
      const float* xrow = xn + ((size_t)c2 * HD + i) * WD;
#pragma unroll
      for (int e = 0; e < 4; ++e) {
        const int jp = lnb + e + q - 3;
        Bs[lkb][lnb + e] = ((unsigned)jp < (unsigned)WD) ? xrow[jp] : 0.f;
      }
    }
    __syncthreads();
#pragma unroll
    for (int k = 0; k < BK; ++k) {
      const float4 a4 = *(const float4*)&As[k][tm << 2];
      const float4 b4 = *(const float4*)&Bs[k][tn << 2];
      const float ar[4] = {a4.x, a4.y, a4.z, a4.w};
      const float br[4] = {b4.x, b4.y, b4.z, b4.w};
#pragma unroll
      for (int r = 0; r < 4; ++r)
#pragma unroll
        for (int c = 0; c < 4; ++c)
          acc[r][c] = fmaf(ar[r], br[c], acc[r][c]);
    }
    __syncthreads();
  }

  // epilogue: subtract depthwise t6, write out
  const int cbase = m0 + (tm << 2);
  const int jbase = tn << 2;
#pragma unroll
  for (int r = 0; r < 4; ++r) {
    const int c = cbase + r;
    const float w0 = w6[c * 3 + 0], w1 = w6[c * 3 + 1], w2 = w6[c * 3 + 2];
    const float* xc  = xn + (size_t)c * SD;
    const float* p4c = p4 + (size_t)c * SD;
    float vv[4];
#pragma unroll
    for (int cc = 0; cc < 4; ++cc) {
      const int j  = jbase + cc;
      const int jm = (j - 1) & 63;
      float t6 = w1 * p4c[i * WD + jm] * xc[i * WD + jm];
      if (i >= 3)  t6 += w0 * p4c[(i - 3) * WD + jm] * xc[(i - 3) * WD + jm];
      if (i <= 60) t6 += w2 * p4c[(i + 3) * WD + jm] * xc[(i + 3) * WD + jm];
      vv[cc] = acc[r][cc] - t6;
    }
    *(float4*)(outp + ((size_t)(n * CD + c)) * SD + s0 + jbase) =
        make_float4(vv[0], vv[1], vv[2], vv[3]);
  }
}

extern "C" void kernel_launch(void* const* d_in, const int* in_sizes, int n_in,
                              void* d_out, int out_size, void* d_ws, size_t ws_size,
                              hipStream_t stream) {
  const float* x  = (const float*)d_in[0];
  const float* p2 = (const float*)d_in[1];
  const float* p3 = (const float*)d_in[2];
  const float* p4 = (const float*)d_in[3];
  const float* w6 = (const float*)d_in[4];
  const float* w7 = (const float*)d_in[5];
  float* outp = (float*)d_out;

  float* t8 = (float*)d_ws;                          // 16*128*896 f32 = 7.34 MB
  float* mm = t8 + (size_t)NB * CD * K7;             // another 7.34 MB

  dim3 blk(256);
  t8_kernel<<<dim3(K7 / BN, CD / BM, NB), blk, 0, stream>>>(x, p2, p3, t8);
  m_kernel<<<dim3(K7 / BN, (NB * CD) / BM), blk, 0, stream>>>(t8, w7, mm);
  out_kernel<<<dim3(SD / BN, CD / BM, NB), blk, 0, stream>>>(x, mm, p4, w6, outp);
}

// Round 2
// 245.740 us; speedup vs baseline: 2.4967x; 2.4967x over previous
//
#include <hip/hip_runtime.h>

#define NB 16
#define CD 128
#define HD 64
#define WD 64
#define SD 4096   // H*W
#define K7 896    // 7*C

typedef float  f32x4  __attribute__((ext_vector_type(4)));
typedef __bf16 bf16x8 __attribute__((ext_vector_type(8)));

// ---------------------------------------------------------------------------
// prep: x (f32) -> xbf (bf16), 8 elems/thread
// ---------------------------------------------------------------------------
__global__ __launch_bounds__(256)
void cvt_x_kernel(const float* __restrict__ x, __bf16* __restrict__ xbf) {
  const int idx = (blockIdx.x * 256 + threadIdx.x) * 8;
  const float4 a = *(const float4*)(x + idx);
  const float4 b = *(const float4*)(x + idx + 4);
  bf16x8 v;
  v[0] = (__bf16)a.x; v[1] = (__bf16)a.y; v[2] = (__bf16)a.z; v[3] = (__bf16)a.w;
  v[4] = (__bf16)b.x; v[5] = (__bf16)b.y; v[6] = (__bf16)b.z; v[7] = (__bf16)b.w;
  *(bf16x8*)(xbf + idx) = v;
}

// ---------------------------------------------------------------------------
// prep: w7t[k2][k'] = bf16(w7[k'][k2])   (896 x 896), 64x64 LDS tiles
// ---------------------------------------------------------------------------
__global__ __launch_bounds__(256)
void w7t_kernel(const float* __restrict__ w7, __bf16* __restrict__ w7t) {
  __shared__ __bf16 tile[64][65];
  const int b2 = blockIdx.x * 64;   // k2 base
  const int bp = blockIdx.y * 64;   // k' base
  const int t  = threadIdx.x;
  const int col = t & 63;
  const int r0  = t >> 6;
#pragma unroll
  for (int rr = 0; rr < 16; ++rr) {
    const int row = rr * 4 + r0;    // k' offset
    tile[col][row] = (__bf16)w7[(size_t)(bp + row) * K7 + b2 + col];
  }
  __syncthreads();
#pragma unroll
  for (int rr = 0; rr < 16; ++rr) {
    const int row = rr * 4 + r0;    // k2 offset
    w7t[(size_t)(b2 + row) * K7 + bp + col] = tile[row][col];
  }
}

// ---------------------------------------------------------------------------
// MFMA GEMM 1: T8[n,c1,k'] = (1/64) sum_s xbf[n,c1,s] * T3[n,k',s]
// block tile 128(M=c1) x 64(N=k'), BK=32, 4 waves (each 64x32 = 4x2 frags)
// LDS layout [kgroup][row][8bf16] -> every frag = 1 conflict-free ds_read_b128
// ---------------------------------------------------------------------------
__global__ __launch_bounds__(256)
void t8_mfma(const float* __restrict__ x, const __bf16* __restrict__ xbf,
             const float* __restrict__ p2, const float* __restrict__ p3,
             __bf16* __restrict__ t8bf) {
  __shared__ __bf16 As[4 * 128 * 8];   // 8 KB
  __shared__ __bf16 Bs[4 * 64 * 8];    // 4 KB
  const int n  = blockIdx.z;
  const int n0 = blockIdx.x * 64;
  const int t  = threadIdx.x;
  const int lane = t & 63, wid = t >> 6;
  const int wm = wid & 1, wn = wid >> 1;
  const int l16 = lane & 15, lg = lane >> 4;

  const __bf16* xbn = xbf + (size_t)n * CD * SD;
  // A staging: 512 cells [kg(4)][row(128)], thread t does cells t and t+256
  const int a_row = t & 127;
  const __bf16* a_src0 = xbn + (size_t)a_row * SD + (t >> 7) * 8;
  // B staging: cell = [sg(4)][kpl(64)] = thread t
  const int sg = t >> 6, kpl = t & 63;
  const int kp = n0 + kpl;
  const int c2 = kp / 7, kk = kp - c2 * 7;
  const int drow = 2 * kk - 6;
  const float* xpl = x + ((size_t)n * CD + c2) * SD;
  const float p3v = p3[kp];
  float g[2][8];
#pragma unroll
  for (int h2 = 0; h2 < 2; ++h2)
#pragma unroll
    for (int e = 0; e < 8; ++e)
      g[h2][e] = p3v * p2[c2 * WD + h2 * 32 + sg * 8 + e];

  f32x4 acc[4][2] = {};
  for (int s0 = 0; s0 < SD; s0 += 32) {
    *(int4*)&As[(size_t)t * 8]         = *(const int4*)(a_src0 + s0);
    *(int4*)&As[(size_t)(t + 256) * 8] = *(const int4*)(a_src0 + s0 + 16);
    {
      const int ip = (s0 >> 6) + drow;
      const int h2 = (s0 >> 5) & 1;
      bf16x8 bv;
      if ((unsigned)ip < (unsigned)HD) {
        const float* xr = xpl + ip * WD + h2 * 32 + sg * 8;
        const float4 u0 = *(const float4*)xr;
        const float4 u1 = *(const float4*)(xr + 4);
        bv[0] = (__bf16)(u0.x * g[h2][0]); bv[1] = (__bf16)(u0.y * g[h2][1]);
        bv[2] = (__bf16)(u0.z * g[h2][2]); bv[3] = (__bf16)(u0.w * g[h2][3]);
        bv[4] = (__bf16)(u1.x * g[h2][4]); bv[5] = (__bf16)(u1.y * g[h2][5]);
        bv[6] = (__bf16)(u1.z * g[h2][6]); bv[7] = (__bf16)(u1.w * g[h2][7]);
      } else {
#pragma unroll
        for (int e = 0; e < 8; ++e) bv[e] = (__bf16)0.f;
      }
      *(bf16x8*)&Bs[(size_t)t * 8] = bv;
    }
    __syncthreads();
    bf16x8 af[4], bfr[2];
#pragma unroll
    for (int fm = 0; fm < 4; ++fm)
      af[fm] = *(const bf16x8*)&As[(size_t)(lg * 128 + wm * 64 + fm * 16 + l16) * 8];
#pragma unroll
    for (int fn = 0; fn < 2; ++fn)
      bfr[fn] = *(const bf16x8*)&Bs[(size_t)(lg * 64 + wn * 32 + fn * 16 + l16) * 8];
#pragma unroll
    for (int fm = 0; fm < 4; ++fm)
#pragma unroll
      for (int fn = 0; fn < 2; ++fn)
        acc[fm][fn] = __builtin_amdgcn_mfma_f32_16x16x32_bf16(af[fm], bfr[fn], acc[fm][fn], 0, 0, 0);
    __syncthreads();
  }
  const int colb = n0 + wn * 32 + l16;
#pragma unroll
  for (int fm = 0; fm < 4; ++fm)
#pragma unroll
    for (int r = 0; r < 4; ++r) {
      const int c1 = wm * 64 + fm * 16 + lg * 4 + r;
      __bf16* orow = t8bf + ((size_t)n * CD + c1) * K7 + colb;
#pragma unroll
      for (int fn = 0; fn < 2; ++fn)
        orow[fn * 16] = (__bf16)(acc[fm][fn][r] * (1.0f / 64.0f));
    }
}

// ---------------------------------------------------------------------------
// MFMA GEMM 2: M = (T8 (2048x896) * w7t^T) / sqrt(896)   (NT via w7t[k2][k'])
// ---------------------------------------------------------------------------
__global__ __launch_bounds__(256)
void m_mfma(const __bf16* __restrict__ t8bf, const __bf16* __restrict__ w7t,
            __bf16* __restrict__ mmbf) {
  __shared__ __bf16 As[4 * 128 * 8];
  __shared__ __bf16 Bs[4 * 64 * 8];
  const int m0 = blockIdx.y * 128;
  const int n0 = blockIdx.x * 64;
  const int t  = threadIdx.x;
  const int lane = t & 63, wid = t >> 6;
  const int wm = wid & 1, wn = wid >> 1;
  const int l16 = lane & 15, lg = lane >> 4;

  const int a_row = t & 127;
  const __bf16* a_src0 = t8bf + (size_t)(m0 + a_row) * K7 + (t >> 7) * 8;
  const int bcol = t & 63;
  const __bf16* b_src = w7t + (size_t)(n0 + bcol) * K7 + (t >> 6) * 8;

  f32x4 acc[4][2] = {};
  for (int k0 = 0; k0 < K7; k0 += 32) {
    *(int4*)&As[(size_t)t * 8]         = *(const int4*)(a_src0 + k0);
    *(int4*)&As[(size_t)(t + 256) * 8] = *(const int4*)(a_src0 + k0 + 16);
    *(int4*)&Bs[(size_t)t * 8]         = *(const int4*)(b_src + k0);
    __syncthreads();
    bf16x8 af[4], bfr[2];
#pragma unroll
    for (int fm = 0; fm < 4; ++fm)
      af[fm] = *(const bf16x8*)&As[(size_t)(lg * 128 + wm * 64 + fm * 16 + l16) * 8];
#pragma unroll
    for (int fn = 0; fn < 2; ++fn)
      bfr[fn] = *(const bf16x8*)&Bs[(size_t)(lg * 64 + wn * 32 + fn * 16 + l16) * 8];
#pragma unroll
    for (int fm = 0; fm < 4; ++fm)
#pragma unroll
      for (int fn = 0; fn < 2; ++fn)
        acc[fm][fn] = __builtin_amdgcn_mfma_f32_16x16x32_bf16(af[fm], bfr[fn], acc[fm][fn], 0, 0, 0);
    __syncthreads();
  }
  const float sc = 0.033407655f;  // 1/sqrt(896)
  const int colb = n0 + wn * 32 + l16;
#pragma unroll
  for (int fm = 0; fm < 4; ++fm)
#pragma unroll
    for (int r = 0; r < 4; ++r) {
      const int mr = m0 + wm * 64 + fm * 16 + lg * 4 + r;
      __bf16* orow = mmbf + (size_t)mr * K7 + colb;
#pragma unroll
      for (int fn = 0; fn < 2; ++fn)
        orow[fn * 16] = (__bf16)(acc[fm][fn][r] * sc);
    }
}

// ---------------------------------------------------------------------------
// MFMA GEMM 3: out[n,c,i*64+j] = sum_k2 M[n,c,k2]*xbf[n,c2,i,j+q-3] - t6
// block tile 128(M=c) x 64(N=s, one image row i), BK=32
// ---------------------------------------------------------------------------
__global__ __launch_bounds__(256)
void out_mfma(const float* __restrict__ x, const __bf16* __restrict__ xbf,
              const __bf16* __restrict__ mmbf,
              const float* __restrict__ p4, const float* __restrict__ w6,
              float* __restrict__ outp) {
  __shared__ __bf16 As[4 * 128 * 8];
  __shared__ __bf16 Bs[4 * 64 * 8];
  const int n = blockIdx.z;
  const int i = blockIdx.x;          // image row; s tile = [i*64, i*64+64)
  const int t = threadIdx.x;
  const int lane = t & 63, wid = t >> 6;
  const int wm = wid & 1, wn = wid >> 1;
  const int l16 = lane & 15, lg = lane >> 4;

  const __bf16* Mn  = mmbf + (size_t)n * CD * K7;
  const __bf16* xbn = xbf + (size_t)n * CD * SD;
  const int a_row = t & 127;
  const __bf16* a_src0 = Mn + (size_t)a_row * K7 + (t >> 7) * 8;
  const int sg2 = t >> 6, scol = t & 63;

  f32x4 acc[4][2] = {};
  for (int k0 = 0; k0 < K7; k0 += 32) {
    *(int4*)&As[(size_t)t * 8]         = *(const int4*)(a_src0 + k0);
    *(int4*)&As[(size_t)(t + 256) * 8] = *(const int4*)(a_src0 + k0 + 16);
    {
      bf16x8 bv;
#pragma unroll
      for (int e = 0; e < 8; ++e) {
        const int k2 = k0 + sg2 * 8 + e;
        const int c2 = k2 / 7;
        const int q  = k2 - c2 * 7;
        const int jp = scol + q - 3;
        bv[e] = ((unsigned)jp < (unsigned)WD)
                  ? xbn[(size_t)c2 * SD + i * WD + jp] : (__bf16)0.f;
      }
      *(bf16x8*)&Bs[(size_t)t * 8] = bv;
    }
    __syncthreads();
    bf16x8 af[4], bfr[2];
#pragma unroll
    for (int fm = 0; fm < 4; ++fm)
      af[fm] = *(const bf16x8*)&As[(size_t)(lg * 128 + wm * 64 + fm * 16 + l16) * 8];
#pragma unroll
    for (int fn = 0; fn < 2; ++fn)
      bfr[fn] = *(const bf16x8*)&Bs[(size_t)(lg * 64 + wn * 32 + fn * 16 + l16) * 8];
#pragma unroll
    for (int fm = 0; fm < 4; ++fm)
#pragma unroll
      for (int fn = 0; fn < 2; ++fn)
        acc[fm][fn] = __builtin_amdgcn_mfma_f32_16x16x32_bf16(af[fm], bfr[fn], acc[fm][fn], 0, 0, 0);
    __syncthreads();
  }

  const float* xn = x + (size_t)n * CD * SD;
#pragma unroll
  for (int fm = 0; fm < 4; ++fm)
#pragma unroll
    for (int r = 0; r < 4; ++r) {
      const int c = wm * 64 + fm * 16 + lg * 4 + r;
      const float w60 = w6[c * 3 + 0], w61 = w6[c * 3 + 1], w62 = w6[c * 3 + 2];
      const float* xc  = xn + (size_t)c * SD;
      const float* p4c = p4 + (size_t)c * SD;
#pragma unroll
      for (int fn = 0; fn < 2; ++fn) {
        const int j  = wn * 32 + fn * 16 + l16;
        const int jm = (j - 1) & 63;
        float t6 = w61 * p4c[i * WD + jm] * xc[i * WD + jm];
        if (i >= 3)  t6 += w60 * p4c[(i - 3) * WD + jm] * xc[(i - 3) * WD + jm];
        if (i <= 60) t6 += w62 * p4c[(i + 3) * WD + jm] * xc[(i + 3) * WD + jm];
        outp[((size_t)(n * CD + c)) * SD + i * WD + j] = acc[fm][fn][r] - t6;
      }
    }
}

extern "C" void kernel_launch(void* const* d_in, const int* in_sizes, int n_in,
                              void* d_out, int out_size, void* d_ws, size_t ws_size,
                              hipStream_t stream) {
  const float* x  = (const float*)d_in[0];
  const float* p2 = (const float*)d_in[1];
  const float* p3 = (const float*)d_in[2];
  const float* p4 = (const float*)d_in[3];
  const float* w6 = (const float*)d_in[4];
  const float* w7 = (const float*)d_in[5];
  float* outp = (float*)d_out;

  __bf16* xbf  = (__bf16*)d_ws;                       // 8,388,608 elems (16.8 MB)
  __bf16* t8bf = xbf  + (size_t)NB * CD * SD;         // 1,835,008 (3.7 MB)
  __bf16* mmbf = t8bf + (size_t)NB * CD * K7;         // 1,835,008 (3.7 MB)
  __bf16* w7t  = mmbf + (size_t)NB * CD * K7;         // 802,816  (1.6 MB)

  cvt_x_kernel<<<dim3((NB * CD * SD) / (256 * 8)), 256, 0, stream>>>(x, xbf);
  w7t_kernel<<<dim3(14, 14), 256, 0, stream>>>(w7, w7t);
  t8_mfma<<<dim3(14, 1, NB), 256, 0, stream>>>(x, xbf, p2, p3, t8bf);
  m_mfma<<<dim3(14, 16), 256, 0, stream>>>(t8bf, w7t, mmbf);
  out_mfma<<<dim3(64, 1, NB), 256, 0, stream>>>(x, xbf, mmbf, p4, w6, outp);
}

// Round 3
// 175.051 us; speedup vs baseline: 3.5050x; 1.4038x over previous
//
#include <hip/hip_runtime.h>

#define NB 16
#define CD 128
#define HD 64
#define WD 64
#define SD 4096   // H*W
#define K7 896    // 7*C

typedef float  f32x4  __attribute__((ext_vector_type(4)));
typedef __bf16 bf16x8 __attribute__((ext_vector_type(8)));
typedef __bf16 bf16x4 __attribute__((ext_vector_type(4)));

// ---------------------------------------------------------------------------
// prep: x (f32) -> xbf (bf16), 8 elems/thread
// ---------------------------------------------------------------------------
__global__ __launch_bounds__(256)
void cvt_x_kernel(const float* __restrict__ x, __bf16* __restrict__ xbf) {
  const int idx = (blockIdx.x * 256 + threadIdx.x) * 8;
  const float4 a = *(const float4*)(x + idx);
  const float4 b = *(const float4*)(x + idx + 4);
  bf16x8 v;
  v[0] = (__bf16)a.x; v[1] = (__bf16)a.y; v[2] = (__bf16)a.z; v[3] = (__bf16)a.w;
  v[4] = (__bf16)b.x; v[5] = (__bf16)b.y; v[6] = (__bf16)b.z; v[7] = (__bf16)b.w;
  *(bf16x8*)(xbf + idx) = v;
}

// ---------------------------------------------------------------------------
// prep: w7t[k2][k'] = bf16(w7[k'][k2])   (896 x 896), 64x64 LDS tiles
// ---------------------------------------------------------------------------
__global__ __launch_bounds__(256)
void w7t_kernel(const float* __restrict__ w7, __bf16* __restrict__ w7t) {
  __shared__ __bf16 tile[64][65];
  const int b2 = blockIdx.x * 64;   // k2 base
  const int bp = blockIdx.y * 64;   // k' base
  const int t  = threadIdx.x;
  const int col = t & 63;
  const int r0  = t >> 6;
#pragma unroll
  for (int rr = 0; rr < 16; ++rr) {
    const int row = rr * 4 + r0;
    tile[col][row] = (__bf16)w7[(size_t)(bp + row) * K7 + b2 + col];
  }
  __syncthreads();
#pragma unroll
  for (int rr = 0; rr < 16; ++rr) {
    const int row = rr * 4 + r0;
    w7t[(size_t)(b2 + row) * K7 + bp + col] = tile[row][col];
  }
}

// ---------------------------------------------------------------------------
// MFMA GEMM 1 (split-K): per (n, kc): partial T8 over s-chunk of NSTEP*32.
// block tile 128(M=c1) x 64(N=k'), BK=32, 4 waves, 1-barrier double buffer.
// ---------------------------------------------------------------------------
template<int NSTEP, bool PARTIAL>
__global__ __launch_bounds__(256)
void t8_mfma(const __bf16* __restrict__ xbf,
             const float* __restrict__ p2, const float* __restrict__ p3,
             float* __restrict__ part, __bf16* __restrict__ t8bf) {
  __shared__ __bf16 As[2][4 * 128 * 8];
  __shared__ __bf16 Bs[2][4 * 64 * 8];
  const int n  = blockIdx.z;
  const int kc = blockIdx.y;
  const int n0 = blockIdx.x * 64;
  const int sbase = kc * (NSTEP * 32);
  const int t = threadIdx.x;
  const int lane = t & 63, wid = t >> 6;
  const int wm = wid & 1, wn = wid >> 1;
  const int l16 = lane & 15, lg = lane >> 4;

  const __bf16* xbn = xbf + (size_t)n * CD * SD;
  const __bf16* a_src = xbn + (size_t)(t & 127) * SD + (t >> 7) * 8 + sbase;

  // B: k' = n0 + (t&63), staged k-subgroup sg = t>>6
  const int sg = t >> 6;
  const int kp = n0 + (t & 63);
  const int c2 = kp / 7, kk = kp - c2 * 7;
  const int drow = 2 * kk - 6;
  const __bf16* xpl = xbn + (size_t)c2 * SD + sg * 8;
  const float p3v = p3[kp];
  float g[2][8];
#pragma unroll
  for (int h2 = 0; h2 < 2; ++h2)
#pragma unroll
    for (int e = 0; e < 8; ++e)
      g[h2][e] = p3v * p2[c2 * WD + h2 * 32 + sg * 8 + e];

  int4 a0, a1;
  bf16x8 u = {};
  bool val;

#define T8_ISSUE(S0) do {                                              \
    a0 = *(const int4*)(a_src + ((S0) - sbase));                       \
    a1 = *(const int4*)(a_src + ((S0) - sbase) + 16);                  \
    const int ip_ = ((S0) >> 6) + drow;                                \
    val = ((unsigned)ip_ < (unsigned)HD);                              \
    if (val) u = *(const bf16x8*)(xpl + ip_ * WD + (((S0) >> 5) & 1) * 32); \
  } while (0)

#define T8_STAGE(B, H2) do {                                           \
    *(int4*)&As[B][(size_t)t * 8]         = a0;                        \
    *(int4*)&As[B][(size_t)(t + 256) * 8] = a1;                        \
    bf16x8 bv;                                                         \
    _Pragma("unroll")                                                  \
    for (int e = 0; e < 8; ++e)                                        \
      bv[e] = val ? (__bf16)((float)u[e] * g[H2][e]) : (__bf16)0.f;    \
    *(bf16x8*)&Bs[B][(size_t)t * 8] = bv;                              \
  } while (0)

  T8_ISSUE(sbase);
  T8_STAGE(0, (sbase >> 5) & 1);

  f32x4 acc[4][2] = {};
  for (int st = 0; st < NSTEP; ++st) {
    __syncthreads();
    const int cur = st & 1;
    const int s0n = sbase + (st + 1) * 32;
    if (st + 1 < NSTEP) T8_ISSUE(s0n);
    bf16x8 af[4], bfr[2];
#pragma unroll
    for (int fm = 0; fm < 4; ++fm)
      af[fm] = *(const bf16x8*)&As[cur][(size_t)(lg * 128 + wm * 64 + fm * 16 + l16) * 8];
#pragma unroll
    for (int fn = 0; fn < 2; ++fn)
      bfr[fn] = *(const bf16x8*)&Bs[cur][(size_t)(lg * 64 + wn * 32 + fn * 16 + l16) * 8];
#pragma unroll
    for (int fm = 0; fm < 4; ++fm)
#pragma unroll
      for (int fn = 0; fn < 2; ++fn)
        acc[fm][fn] = __builtin_amdgcn_mfma_f32_16x16x32_bf16(af[fm], bfr[fn], acc[fm][fn], 0, 0, 0);
    if (st + 1 < NSTEP) T8_STAGE(cur ^ 1, (s0n >> 5) & 1);
  }
#undef T8_ISSUE
#undef T8_STAGE

  const int colb = n0 + wn * 32 + l16;
  if constexpr (PARTIAL) {
    float* pb = part + (size_t)kc * (NB * CD * K7) + (size_t)n * CD * K7;
#pragma unroll
    for (int fm = 0; fm < 4; ++fm)
#pragma unroll
      for (int r = 0; r < 4; ++r) {
        const int c1 = wm * 64 + fm * 16 + lg * 4 + r;
        float* orow = pb + (size_t)c1 * K7 + colb;
        orow[0]  = acc[fm][0][r];
        orow[16] = acc[fm][1][r];
      }
  } else {
#pragma unroll
    for (int fm = 0; fm < 4; ++fm)
#pragma unroll
      for (int r = 0; r < 4; ++r) {
        const int c1 = wm * 64 + fm * 16 + lg * 4 + r;
        __bf16* orow = t8bf + ((size_t)n * CD + c1) * K7 + colb;
        orow[0]  = (__bf16)(acc[fm][0][r] * (1.f / 64.f));
        orow[16] = (__bf16)(acc[fm][1][r] * (1.f / 64.f));
      }
  }
}

// ---------------------------------------------------------------------------
// reduce split-K partials -> t8bf (scale 1/64)
// ---------------------------------------------------------------------------
template<int KC>
__global__ __launch_bounds__(256)
void t8_reduce(const float* __restrict__ part, __bf16* __restrict__ t8bf) {
  const size_t idx = ((size_t)blockIdx.x * 256 + threadIdx.x) * 4;
  const size_t stride = (size_t)NB * CD * K7;
  float4 s = *(const float4*)(part + idx);
#pragma unroll
  for (int c = 1; c < KC; ++c) {
    const float4 p = *(const float4*)(part + c * stride + idx);
    s.x += p.x; s.y += p.y; s.z += p.z; s.w += p.w;
  }
  bf16x4 v;
  v[0] = (__bf16)(s.x * (1.f / 64.f));
  v[1] = (__bf16)(s.y * (1.f / 64.f));
  v[2] = (__bf16)(s.z * (1.f / 64.f));
  v[3] = (__bf16)(s.w * (1.f / 64.f));
  *(bf16x4*)(t8bf + idx) = v;
}

// ---------------------------------------------------------------------------
// MFMA GEMM 2: M = (T8 (2048x896) * w7) / sqrt(896), NT via w7t[k2][k']
// ---------------------------------------------------------------------------
__global__ __launch_bounds__(256)
void m_mfma(const __bf16* __restrict__ t8bf, const __bf16* __restrict__ w7t,
            __bf16* __restrict__ mmbf) {
  __shared__ __bf16 As[2][4 * 128 * 8];
  __shared__ __bf16 Bs[2][4 * 64 * 8];
  const int m0 = blockIdx.y * 128;
  const int n0 = blockIdx.x * 64;
  const int t  = threadIdx.x;
  const int lane = t & 63, wid = t >> 6;
  const int wm = wid & 1, wn = wid >> 1;
  const int l16 = lane & 15, lg = lane >> 4;

  const __bf16* a_src = t8bf + (size_t)(m0 + (t & 127)) * K7 + (t >> 7) * 8;
  const __bf16* b_src = w7t + (size_t)(n0 + (t & 63)) * K7 + (t >> 6) * 8;

  int4 a0 = *(const int4*)a_src;
  int4 a1 = *(const int4*)(a_src + 16);
  int4 b0 = *(const int4*)b_src;
  *(int4*)&As[0][(size_t)t * 8]         = a0;
  *(int4*)&As[0][(size_t)(t + 256) * 8] = a1;
  *(int4*)&Bs[0][(size_t)t * 8]         = b0;

  f32x4 acc[4][2] = {};
  const int NSTEP = K7 / 32;
  for (int st = 0; st < NSTEP; ++st) {
    __syncthreads();
    const int cur = st & 1;
    if (st + 1 < NSTEP) {
      a0 = *(const int4*)(a_src + (st + 1) * 32);
      a1 = *(const int4*)(a_src + (st + 1) * 32 + 16);
      b0 = *(const int4*)(b_src + (st + 1) * 32);
    }
    bf16x8 af[4], bfr[2];
#pragma unroll
    for (int fm = 0; fm < 4; ++fm)
      af[fm] = *(const bf16x8*)&As[cur][(size_t)(lg * 128 + wm * 64 + fm * 16 + l16) * 8];
#pragma unroll
    for (int fn = 0; fn < 2; ++fn)
      bfr[fn] = *(const bf16x8*)&Bs[cur][(size_t)(lg * 64 + wn * 32 + fn * 16 + l16) * 8];
#pragma unroll
    for (int fm = 0; fm < 4; ++fm)
#pragma unroll
      for (int fn = 0; fn < 2; ++fn)
        acc[fm][fn] = __builtin_amdgcn_mfma_f32_16x16x32_bf16(af[fm], bfr[fn], acc[fm][fn], 0, 0, 0);
    if (st + 1 < NSTEP) {
      *(int4*)&As[cur ^ 1][(size_t)t * 8]         = a0;
      *(int4*)&As[cur ^ 1][(size_t)(t + 256) * 8] = a1;
      *(int4*)&Bs[cur ^ 1][(size_t)t * 8]         = b0;
    }
  }
  const float sc = 0.033407655f;  // 1/sqrt(896)
  const int colb = n0 + wn * 32 + l16;
#pragma unroll
  for (int fm = 0; fm < 4; ++fm)
#pragma unroll
    for (int r = 0; r < 4; ++r) {
      const int mr = m0 + wm * 64 + fm * 16 + lg * 4 + r;
      __bf16* orow = mmbf + (size_t)mr * K7 + colb;
      orow[0]  = (__bf16)(acc[fm][0][r] * sc);
      orow[16] = (__bf16)(acc[fm][1][r] * sc);
    }
}

// ---------------------------------------------------------------------------
// MFMA GEMM 3: out[n,c,i*64+j] = sum_k2 M[n,c,k2]*xbf[n,c2,i,j+q-3] - t6
// ---------------------------------------------------------------------------
__global__ __launch_bounds__(256)
void out_mfma(const float* __restrict__ x, const __bf16* __restrict__ xbf,
              const __bf16* __restrict__ mmbf,
              const float* __restrict__ p4, const float* __restrict__ w6,
              float* __restrict__ outp) {
  __shared__ __bf16 As[2][4 * 128 * 8];
  __shared__ __bf16 Bs[2][4 * 64 * 8];
  const int n = blockIdx.z;
  const int i = blockIdx.x;
  const int t = threadIdx.x;
  const int lane = t & 63, wid = t >> 6;
  const int wm = wid & 1, wn = wid >> 1;
  const int l16 = lane & 15, lg = lane >> 4;

  const __bf16* xbn = xbf + (size_t)n * CD * SD;
  const __bf16* a_src = mmbf + (size_t)n * CD * K7 + (size_t)(t & 127) * K7 + (t >> 7) * 8;
  const int sg2 = t >> 6, scol = t & 63;

  int4 a0, a1;
  bf16x8 ub;

#define OUT_ISSUE(K0) do {                                             \
    a0 = *(const int4*)(a_src + (K0));                                 \
    a1 = *(const int4*)(a_src + (K0) + 16);                            \
    _Pragma("unroll")                                                  \
    for (int e = 0; e < 8; ++e) {                                      \
      const int k2 = (K0) + sg2 * 8 + e;                               \
      const int c2_ = k2 / 7;                                          \
      const int q_  = k2 - c2_ * 7;                                    \
      const int jp_ = scol + q_ - 3;                                   \
      ub[e] = ((unsigned)jp_ < (unsigned)WD)                           \
                ? xbn[(size_t)c2_ * SD + i * WD + jp_] : (__bf16)0.f;  \
    }                                                                  \
  } while (0)

#define OUT_STAGE(B) do {                                              \
    *(int4*)&As[B][(size_t)t * 8]         = a0;                        \
    *(int4*)&As[B][(size_t)(t + 256) * 8] = a1;                        \
    *(bf16x8*)&Bs[B][(size_t)t * 8]       = ub;                        \
  } while (0)

  OUT_ISSUE(0);
  OUT_STAGE(0);

  f32x4 acc[4][2] = {};
  const int NSTEP = K7 / 32;
  for (int st = 0; st < NSTEP; ++st) {
    __syncthreads();
    const int cur = st & 1;
    if (st + 1 < NSTEP) OUT_ISSUE((st + 1) * 32);
    bf16x8 af[4], bfr[2];
#pragma unroll
    for (int fm = 0; fm < 4; ++fm)
      af[fm] = *(const bf16x8*)&As[cur][(size_t)(lg * 128 + wm * 64 + fm * 16 + l16) * 8];
#pragma unroll
    for (int fn = 0; fn < 2; ++fn)
      bfr[fn] = *(const bf16x8*)&Bs[cur][(size_t)(lg * 64 + wn * 32 + fn * 16 + l16) * 8];
#pragma unroll
    for (int fm = 0; fm < 4; ++fm)
#pragma unroll
      for (int fn = 0; fn < 2; ++fn)
        acc[fm][fn] = __builtin_amdgcn_mfma_f32_16x16x32_bf16(af[fm], bfr[fn], acc[fm][fn], 0, 0, 0);
    if (st + 1 < NSTEP) OUT_STAGE(cur ^ 1);
  }
#undef OUT_ISSUE
#undef OUT_STAGE

  const float* xn = x + (size_t)n * CD * SD;
#pragma unroll
  for (int fm = 0; fm < 4; ++fm)
#pragma unroll
    for (int r = 0; r < 4; ++r) {
      const int c = wm * 64 + fm * 16 + lg * 4 + r;
      const float w60 = w6[c * 3 + 0], w61 = w6[c * 3 + 1], w62 = w6[c * 3 + 2];
      const float* xc  = xn + (size_t)c * SD;
      const float* p4c = p4 + (size_t)c * SD;
#pragma unroll
      for (int fn = 0; fn < 2; ++fn) {
        const int j  = wn * 32 + fn * 16 + l16;
        const int jm = (j - 1) & 63;
        float t6 = w61 * p4c[i * WD + jm] * xc[i * WD + jm];
        if (i >= 3)  t6 += w60 * p4c[(i - 3) * WD + jm] * xc[(i - 3) * WD + jm];
        if (i <= 60) t6 += w62 * p4c[(i + 3) * WD + jm] * xc[(i + 3) * WD + jm];
        outp[((size_t)(n * CD + c)) * SD + i * WD + j] = acc[fm][fn][r] - t6;
      }
    }
}

extern "C" void kernel_launch(void* const* d_in, const int* in_sizes, int n_in,
                              void* d_out, int out_size, void* d_ws, size_t ws_size,
                              hipStream_t stream) {
  const float* x  = (const float*)d_in[0];
  const float* p2 = (const float*)d_in[1];
  const float* p3 = (const float*)d_in[2];
  const float* p4 = (const float*)d_in[3];
  const float* w6 = (const float*)d_in[4];
  const float* w7 = (const float*)d_in[5];
  float* outp = (float*)d_out;

  __bf16* xbf  = (__bf16*)d_ws;                       // 8,388,608 bf16
  __bf16* t8bf = xbf  + (size_t)NB * CD * SD;         // 1,835,008 bf16
  __bf16* mmbf = t8bf + (size_t)NB * CD * K7;         // 1,835,008 bf16
  __bf16* w7t  = mmbf + (size_t)NB * CD * K7;         // 802,816 bf16
  float*  part = (float*)(w7t + (size_t)K7 * K7);     // up to 4 x 1,835,008 f32

  const size_t base_bytes  = ((size_t)NB * CD * SD + 2 * NB * CD * K7 + (size_t)K7 * K7) * 2;
  const size_t chunk_bytes = (size_t)NB * CD * K7 * 4;

  cvt_x_kernel<<<dim3((NB * CD * SD) / (256 * 8)), 256, 0, stream>>>(x, xbf);
  w7t_kernel<<<dim3(14, 14), 256, 0, stream>>>(w7, w7t);

  if (ws_size >= base_bytes + 4 * chunk_bytes) {
    t8_mfma<32, true><<<dim3(14, 4, NB), 256, 0, stream>>>(xbf, p2, p3, part, nullptr);
    t8_reduce<4><<<dim3((NB * CD * K7) / 1024), 256, 0, stream>>>(part, t8bf);
  } else if (ws_size >= base_bytes + 2 * chunk_bytes) {
    t8_mfma<64, true><<<dim3(14, 2, NB), 256, 0, stream>>>(xbf, p2, p3, part, nullptr);
    t8_reduce<2><<<dim3((NB * CD * K7) / 1024), 256, 0, stream>>>(part, t8bf);
  } else {
    t8_mfma<128, false><<<dim3(14, 1, NB), 256, 0, stream>>>(xbf, p2, p3, nullptr, t8bf);
  }

  m_mfma<<<dim3(14, 16), 256, 0, stream>>>(t8bf, w7t, mmbf);
  out_mfma<<<dim3(64, 1, NB), 256, 0, stream>>>(x, xbf, mmbf, p4, w6, outp);
}